// Round 3
// baseline (112.159 us; speedup 1.0000x reference)
//
#include <hip/hip_runtime.h>

// QuantumDMRGLayer: B=2048, L=196, M=16, NBL=10, pos_label=98 (fixed by setup).
// Round-3 design: the round-1/2 kernels were DS-pipe bound (~350 LDS-pipe
// cyc/site/CU: 4 waves x 8 ds_read_b128 of 4-way-redundant rows + scatter
// writes + chunk barriers). This version removes LDS from the site loop:
//   - prep kernel pre-permutes A_mid into d_ws (rotation slots baked in):
//       left  stream slot [n][r] = A[(n-r)&15][n]
//       right stream slot [n][r] = A[n][(n-r)&15]
//     layout: WS[strm*100*512 + p*512 + d*256 + n*16 + r], 100 sites/stream
//     (2 pad sites so the software pipeline can over-read poison harmlessly).
//   - main kernel: 512 blocks x 128 threads, block owns 4 samples, wave 0 =
//     left sweep (p=0..97), wave 1 = right sweep (p=0..95, AM site 193-p).
//     Lane n of each 16-lane group owns v[n] of one sample. Per site, lane n
//     loads its 64 B row per matrix straight global->VGPR (8 dwordx4, L1/L2
//     served), 2-site ping-pong register pipeline, NO barriers in the loop.
//   - m-sum in rotation order via DPP row_ror:r (dst[i]=src[(i-r)&15]),
//     4 independent FMA chains (even/odd slots x 2 matrices).

#define XR 392          // floats per sample row of inputs (196*2)
#define SITE_F 512      // floats per site per stream (2 matrices x 256)
#define STRM_F (100 * SITE_F)  // padded stream region in d_ws

#define DPPV(r) __int_as_float(__builtin_amdgcn_update_dpp(                    \
    __float_as_int(v), __float_as_int(v), 0x120 + (r), 0xF, 0xF, false))

// ---- prep: permute A_mid (194,2,16,16) into rotation-slot layout in d_ws ----
__global__ __launch_bounds__(256)
void perm_kernel(const float* __restrict__ AM, float* __restrict__ WS)
{
    const int bid = blockIdx.x;            // 0..387
    const int tid = threadIdx.x;           // 0..255 = n*16 + r
    const int n = tid >> 4, r = tid & 15;
    const int k = (bid < 196) ? bid : bid - 196;
    const int strm = (bid < 196) ? 0 : 1;
    const int p = k >> 1, d = k & 1;
    float val;
    if (strm == 0) {    // left: site p, element [(n-r)&15][n]
        val = AM[p * 512 + d * 256 + ((n - r) & 15) * 16 + n];
    } else {            // right: site 193-p, element [n][(n-r)&15]
        val = AM[(193 - p) * 512 + d * 256 + n * 16 + ((n - r) & 15)];
    }
    WS[strm * STRM_F + p * SITE_F + d * 256 + tid] = val;
}

__global__ __launch_bounds__(128)
void QuantumDMRGLayer_kernel(const float* __restrict__ X,
                             const float* __restrict__ AL,
                             const float* __restrict__ AR,
                             const float* __restrict__ T,
                             const float* __restrict__ WS,
                             float* __restrict__ OUT)
{
    __shared__ float sX[4 * XR];      // 4 sample rows of inputs
    __shared__ float sV[4][2][16];    // final left/right vectors per sample

    const int tid  = threadIdx.x;
    const int wv   = tid >> 6;        // 0 = left sweep wave, 1 = right
    const int lane = tid & 63;
    const int g    = lane >> 4;       // sample slot 0..3 within block
    const int n    = lane & 15;       // vector component owned by this lane
    const int b0   = (int)blockIdx.x << 2;

    // ---- prologue: stage x rows (4 x 392 floats) ----
    for (int k = tid; k < 4 * 98; k += 128) {
        const int smp = k / 98, w = k - smp * 98;
        const float4 v4 = ((const float4*)(X + (size_t)(b0 + smp) * XR))[w];
        ((float4*)(sX + smp * XR))[w] = v4;
    }
    __syncthreads();

    // ---- init bond vector ----
    const float* Ab = (wv == 0) ? AL : AR;
    const float2 x0 = *(const float2*)(sX + g * XR + (wv == 0 ? 0 : 390));
    float v = x0.x * Ab[n] + x0.y * Ab[16 + n];

    const float* Pb = WS + (wv ? STRM_F : 0) + n * 16;   // lane's row base
    const float* xg = sX + g * XR;

    float4 QA[8], QB[8];
    auto load_site = [&](float4* Q, int p) {
        const float* rp = Pb + p * SITE_F;
        Q[0] = *(const float4*)(rp);        // mat0 slots 0..3
        Q[1] = *(const float4*)(rp + 4);
        Q[2] = *(const float4*)(rp + 8);
        Q[3] = *(const float4*)(rp + 12);
        Q[4] = *(const float4*)(rp + 256);  // mat1 slots 0..3
        Q[5] = *(const float4*)(rp + 260);
        Q[6] = *(const float4*)(rp + 264);
        Q[7] = *(const float4*)(rp + 268);
    };
    // v <- x0*(sum_r vv_r * mat0slot[n][r]) + x1*(... mat1 ...)
    auto step = [&](const float4* Q, int p) {
        const int xo = (wv == 0) ? (2 + 2 * p) : (388 - 2 * p);
        const float2 xs = *(const float2*)(xg + xo);
        const float t1 = DPPV(1),  t2 = DPPV(2),  t3 = DPPV(3),  t4 = DPPV(4);
        const float t5 = DPPV(5),  t6 = DPPV(6),  t7 = DPPV(7),  t8 = DPPV(8);
        const float t9 = DPPV(9),  t10 = DPPV(10), t11 = DPPV(11), t12 = DPPV(12);
        const float t13 = DPPV(13), t14 = DPPV(14), t15 = DPPV(15);
        float a0 = v * Q[0].x;                 float b0 = v * Q[4].x;
        float a1 = t1 * Q[0].y;                float b1 = t1 * Q[4].y;
        a0 = fmaf(t2,  Q[0].z, a0);            b0 = fmaf(t2,  Q[4].z, b0);
        a1 = fmaf(t3,  Q[0].w, a1);            b1 = fmaf(t3,  Q[4].w, b1);
        a0 = fmaf(t4,  Q[1].x, a0);            b0 = fmaf(t4,  Q[5].x, b0);
        a1 = fmaf(t5,  Q[1].y, a1);            b1 = fmaf(t5,  Q[5].y, b1);
        a0 = fmaf(t6,  Q[1].z, a0);            b0 = fmaf(t6,  Q[5].z, b0);
        a1 = fmaf(t7,  Q[1].w, a1);            b1 = fmaf(t7,  Q[5].w, b1);
        a0 = fmaf(t8,  Q[2].x, a0);            b0 = fmaf(t8,  Q[6].x, b0);
        a1 = fmaf(t9,  Q[2].y, a1);            b1 = fmaf(t9,  Q[6].y, b1);
        a0 = fmaf(t10, Q[2].z, a0);            b0 = fmaf(t10, Q[6].z, b0);
        a1 = fmaf(t11, Q[2].w, a1);            b1 = fmaf(t11, Q[6].w, b1);
        a0 = fmaf(t12, Q[3].x, a0);            b0 = fmaf(t12, Q[7].x, b0);
        a1 = fmaf(t13, Q[3].y, a1);            b1 = fmaf(t13, Q[7].y, b1);
        a0 = fmaf(t14, Q[3].z, a0);            b0 = fmaf(t14, Q[7].z, b0);
        a1 = fmaf(t15, Q[3].w, a1);            b1 = fmaf(t15, Q[7].w, b1);
        v = fmaf(xs.x, a0 + a1, xs.y * (b0 + b1));
    };

    const int lim = (wv == 0) ? 98 : 96;   // both even
    load_site(QA, 0);
    for (int p = 0; p < lim; p += 2) {
        load_site(QB, p + 1);
        step(QA, p);
        load_site(QA, p + 2);   // pad sites (<=99) make this always in-bounds
        step(QB, p + 1);
    }

    // ---- epilogue: out[b][l] = sum_{m,n} left[m] T[m][n][l] right[n] ----
    sV[g][wv][n] = v;
    __syncthreads();
    if (tid < 40) {
        const int sm = tid / 10;
        const int l  = tid - sm * 10;
        const float* Rv = &sV[sm][1][0];
        const float4 Ra = *(const float4*)(Rv);
        const float4 Rb = *(const float4*)(Rv + 4);
        const float4 Rc = *(const float4*)(Rv + 8);
        const float4 Rd = *(const float4*)(Rv + 12);
        float acc = 0.f;
#pragma unroll
        for (int m = 0; m < 16; ++m) {
            const float lm = sV[sm][0][m];
            const float* Tp = T + m * 160 + l;
            acc = fmaf(lm * Ra.x, Tp[0],   acc);
            acc = fmaf(lm * Ra.y, Tp[10],  acc);
            acc = fmaf(lm * Ra.z, Tp[20],  acc);
            acc = fmaf(lm * Ra.w, Tp[30],  acc);
            acc = fmaf(lm * Rb.x, Tp[40],  acc);
            acc = fmaf(lm * Rb.y, Tp[50],  acc);
            acc = fmaf(lm * Rb.z, Tp[60],  acc);
            acc = fmaf(lm * Rb.w, Tp[70],  acc);
            acc = fmaf(lm * Rc.x, Tp[80],  acc);
            acc = fmaf(lm * Rc.y, Tp[90],  acc);
            acc = fmaf(lm * Rc.z, Tp[100], acc);
            acc = fmaf(lm * Rc.w, Tp[110], acc);
            acc = fmaf(lm * Rd.x, Tp[120], acc);
            acc = fmaf(lm * Rd.y, Tp[130], acc);
            acc = fmaf(lm * Rd.z, Tp[140], acc);
            acc = fmaf(lm * Rd.w, Tp[150], acc);
        }
        OUT[(b0 + sm) * 10 + l] = acc;
    }
}

extern "C" void kernel_launch(void* const* d_in, const int* in_sizes, int n_in,
                              void* d_out, int out_size, void* d_ws, size_t ws_size,
                              hipStream_t stream)
{
    const float* X  = (const float*)d_in[0];   // (2048,196,2)
    const float* AL = (const float*)d_in[1];   // (2,16)
    const float* AM = (const float*)d_in[2];   // (194,2,16,16)
    const float* AR = (const float*)d_in[3];   // (2,16)
    const float* T  = (const float*)d_in[4];   // (16,16,10)
    (void)in_sizes; (void)n_in; (void)out_size; (void)ws_size;
    float* WS  = (float*)d_ws;                 // 200*512 floats = 400 KB used
    float* OUT = (float*)d_out;                // (2048,10)

    hipLaunchKernelGGL(perm_kernel, dim3(388), dim3(256), 0, stream, AM, WS);
    hipLaunchKernelGGL(QuantumDMRGLayer_kernel, dim3(512), dim3(128), 0, stream,
                       X, AL, AR, T, WS, OUT);
}

// Round 5
// 103.426 us; speedup vs baseline: 1.0844x; 1.0844x over previous
//
#include <hip/hip_runtime.h>

// QuantumDMRGLayer: B=2048, L=196, M=16, NBL=10, pos_label=98 (fixed by setup).
// Round-5 = round-4 with the PIN macro fixed (LLVM can't tie vector asm
// operands; pin the 4 scalar components instead).
// Design recap: rounds 1-3 all measured ~53 us / ~1300 cyc/site, VALUBusy
// ~16%, regardless of inner loop. Round-3's VGPR_Count=32 showed the compiler
// sank all loads to uses (no pipeline) -> per-site serial load latency at
// 1 wave/SIMD. Fixes:
//   - __launch_bounds__(128, 1): 512-VGPR budget so a register pipeline exists.
//   - prep kernel pre-permutes A_mid into WS (rotation slots for DPP row_ror):
//       left  slot [n][r] = A[(n-r)&15][n],  right slot [n][r] = A[n][(n-r)&15]
//     layout WS[strm*100*512 + p*512 + d*256 + n*16 + r] (2 pad sites/stream).
//   - main loop: 4-site chunks, double-buffered LDS, filled via
//     global_load_lds_dwordx4; wave fills AND reads only its own stream region
//     -> NO barriers in the loop; explicit s_waitcnt vmcnt(0) once per chunk,
//     issued 3 sites (~300 cyc) after the fill.
//   - ds_read_b128 fragments: all 4 sample-groups read the same address ->
//     LDS broadcast. 1-site register prefetch (QA/QB ping-pong), PIN anchors
//     fragments in registers so they can't be re-sunk.
//   - m-sum via DPP row_ror:r (dst[i]=src[(i-r)&15]), 4 independent FMA chains.

#define XR 392                 // floats per sample row of inputs (196*2)
#define SITE_F 512             // floats per site per stream (2 matrices x 256)
#define STRM_F (100 * SITE_F)  // padded stream region in WS
#define CHF 2048               // floats per 4-site chunk per stream

#define DPPV(r) __int_as_float(__builtin_amdgcn_update_dpp(                    \
    __float_as_int(v), __float_as_int(v), 0x120 + (r), 0xF, 0xF, false))
#define PIN(q) asm volatile("" : "+v"(q.x), "+v"(q.y), "+v"(q.z), "+v"(q.w))

typedef const __attribute__((address_space(1))) unsigned int* gptr_t;
typedef __attribute__((address_space(3))) unsigned int* lptr_t;

// ---- prep: permute A_mid (194,2,16,16) into rotation-slot layout in WS ----
__global__ __launch_bounds__(256)
void perm_kernel(const float* __restrict__ AM, float* __restrict__ WS)
{
    const int bid = blockIdx.x;            // 0..387
    const int tid = threadIdx.x;           // 0..255 = n*16 + r
    const int n = tid >> 4, r = tid & 15;
    const int k = (bid < 196) ? bid : bid - 196;
    const int strm = (bid < 196) ? 0 : 1;
    const int p = k >> 1, d = k & 1;
    float val;
    if (strm == 0) {    // left: site p, element [(n-r)&15][n]
        val = AM[p * 512 + d * 256 + ((n - r) & 15) * 16 + n];
    } else {            // right: site 193-p, element [n][(n-r)&15]
        val = AM[(193 - p) * 512 + d * 256 + n * 16 + ((n - r) & 15)];
    }
    WS[strm * STRM_F + p * SITE_F + d * 256 + tid] = val;
}

__global__ __launch_bounds__(128, 1)
void QuantumDMRGLayer_kernel(const float* __restrict__ X,
                             const float* __restrict__ AL,
                             const float* __restrict__ AR,
                             const float* __restrict__ T,
                             const float* __restrict__ WS,
                             float* __restrict__ OUT)
{
    __shared__ __align__(16) float sB[2][2][CHF];  // [buf][strm][...] 32 KB
    __shared__ __align__(16) float sX[4 * XR];     // 4 sample rows of inputs
    __shared__ __align__(16) float sT[2560];       // T_out (16,16,10)
    __shared__ float sV[4][2][16];                 // final vectors per sample

    const int tid  = threadIdx.x;
    const int wv   = tid >> 6;        // 0 = left sweep wave, 1 = right
    const int lane = tid & 63;
    const int g    = lane >> 4;       // sample slot 0..3 within block
    const int n    = lane & 15;       // vector component owned by this lane
    const int b0   = (int)blockIdx.x << 2;

    // ---- prologue: stage x rows and T_out ----
    for (int k = tid; k < 4 * 98; k += 128) {
        const int smp = k / 98, w = k - smp * 98;
        const float4 v4 = ((const float4*)(X + (size_t)(b0 + smp) * XR))[w];
        ((float4*)(sX + smp * XR))[w] = v4;
    }
    for (int k = tid; k < 640; k += 128)
        ((float4*)sT)[k] = ((const float4*)T)[k];
    __syncthreads();

    // ---- init bond vector ----
    const float* Ab = (wv == 0) ? AL : AR;
    const float2 x0 = *(const float2*)(sX + g * XR + (wv == 0 ? 0 : 390));
    float v = x0.x * Ab[n] + x0.y * Ab[16 + n];
    const float* xg = sX + g * XR;
    const float* Wb = WS + (wv ? STRM_F : 0);

    // fill chunk c (4 sites of this wave's stream) into LDS buffer buf.
    auto fill = [&](int c, int buf) {
        const float* gp = Wb + c * CHF + lane * 4;
        float* lp = &sB[buf][wv][0];
#pragma unroll
        for (int i = 0; i < 8; ++i)
            __builtin_amdgcn_global_load_lds((gptr_t)(gp + i * 256),
                                             (lptr_t)(lp + i * 256), 16, 0, 0);
    };
    // prefetch site j of buffer buf into 8 float4 (broadcast ds_read_b128).
    auto pre = [&](float4* Q, int buf, int j) {
        const float* rp = &sB[buf][wv][j * SITE_F] + n * 16;
#pragma unroll
        for (int i = 0; i < 4; ++i) {
            Q[i]     = *(const float4*)(rp + 4 * i);
            Q[4 + i] = *(const float4*)(rp + 256 + 4 * i);
        }
    };
    // one site update: v <- x0*(sum_r v_rot(r)*mat0[n][r]) + x1*(...mat1...)
    auto step = [&](float4* Q, int p) {
        PIN(Q[0]); PIN(Q[1]); PIN(Q[2]); PIN(Q[3]);
        PIN(Q[4]); PIN(Q[5]); PIN(Q[6]); PIN(Q[7]);
        const int xo = (wv == 0) ? (2 + 2 * p) : (388 - 2 * p);
        const float2 xs = *(const float2*)(xg + xo);
        const float t1 = DPPV(1),  t2 = DPPV(2),  t3 = DPPV(3),  t4 = DPPV(4);
        const float t5 = DPPV(5),  t6 = DPPV(6),  t7 = DPPV(7),  t8 = DPPV(8);
        const float t9 = DPPV(9),  t10 = DPPV(10), t11 = DPPV(11), t12 = DPPV(12);
        const float t13 = DPPV(13), t14 = DPPV(14), t15 = DPPV(15);
        float a0 = v * Q[0].x;                 float c0 = v * Q[4].x;
        float a1 = t1 * Q[0].y;                float c1 = t1 * Q[4].y;
        a0 = fmaf(t2,  Q[0].z, a0);            c0 = fmaf(t2,  Q[4].z, c0);
        a1 = fmaf(t3,  Q[0].w, a1);            c1 = fmaf(t3,  Q[4].w, c1);
        a0 = fmaf(t4,  Q[1].x, a0);            c0 = fmaf(t4,  Q[5].x, c0);
        a1 = fmaf(t5,  Q[1].y, a1);            c1 = fmaf(t5,  Q[5].y, c1);
        a0 = fmaf(t6,  Q[1].z, a0);            c0 = fmaf(t6,  Q[5].z, c0);
        a1 = fmaf(t7,  Q[1].w, a1);            c1 = fmaf(t7,  Q[5].w, c1);
        a0 = fmaf(t8,  Q[2].x, a0);            c0 = fmaf(t8,  Q[6].x, c0);
        a1 = fmaf(t9,  Q[2].y, a1);            c1 = fmaf(t9,  Q[6].y, c1);
        a0 = fmaf(t10, Q[2].z, a0);            c0 = fmaf(t10, Q[6].z, c0);
        a1 = fmaf(t11, Q[2].w, a1);            c1 = fmaf(t11, Q[6].w, c1);
        a0 = fmaf(t12, Q[3].x, a0);            c0 = fmaf(t12, Q[7].x, c0);
        a1 = fmaf(t13, Q[3].y, a1);            c1 = fmaf(t13, Q[7].y, c1);
        a0 = fmaf(t14, Q[3].z, a0);            c0 = fmaf(t14, Q[7].z, c0);
        a1 = fmaf(t15, Q[3].w, a1);            c1 = fmaf(t15, Q[7].w, c1);
        v = fmaf(xs.x, a0 + a1, xs.y * (c0 + c1));
    };

    // ---- software-pipelined chain: 24 chunks x 4 sites, no barriers ----
    fill(0, 0);
    asm volatile("s_waitcnt vmcnt(0)" ::: "memory");
    float4 QA[8], QB[8];
    pre(QA, 0, 0);
    for (int c = 0; c < 24; ++c) {
        const int buf = c & 1;
        fill(c + 1, buf ^ 1);            // c=23: chunk 24 (right = pad, unused)
        pre(QB, buf, 1); step(QA, 4 * c);
        pre(QA, buf, 2); step(QB, 4 * c + 1);
        pre(QB, buf, 3); step(QA, 4 * c + 2);
        asm volatile("s_waitcnt vmcnt(0)" ::: "memory");
        pre(QA, buf ^ 1, 0); step(QB, 4 * c + 3);
    }
    // left stream has 2 extra sites (96, 97) in chunk 24 (buf 0)
    if (wv == 0) {
        pre(QB, 0, 1); step(QA, 96);
        step(QB, 97);
    }

    // ---- epilogue: out[b][l] = sum_{m,n} left[m] T[m][n][l] right[n] ----
    sV[g][wv][n] = v;
    __syncthreads();
    if (tid < 40) {
        const int sm = tid / 10;
        const int l  = tid - sm * 10;
        const float* Rv = &sV[sm][1][0];
        const float4 Ra = *(const float4*)(Rv);
        const float4 Rb = *(const float4*)(Rv + 4);
        const float4 Rc = *(const float4*)(Rv + 8);
        const float4 Rd = *(const float4*)(Rv + 12);
        float acc = 0.f;
#pragma unroll
        for (int m = 0; m < 16; ++m) {
            const float lm = sV[sm][0][m];
            const float* Tp = sT + m * 160 + l;
            acc = fmaf(lm * Ra.x, Tp[0],   acc);
            acc = fmaf(lm * Ra.y, Tp[10],  acc);
            acc = fmaf(lm * Ra.z, Tp[20],  acc);
            acc = fmaf(lm * Ra.w, Tp[30],  acc);
            acc = fmaf(lm * Rb.x, Tp[40],  acc);
            acc = fmaf(lm * Rb.y, Tp[50],  acc);
            acc = fmaf(lm * Rb.z, Tp[60],  acc);
            acc = fmaf(lm * Rb.w, Tp[70],  acc);
            acc = fmaf(lm * Rc.x, Tp[80],  acc);
            acc = fmaf(lm * Rc.y, Tp[90],  acc);
            acc = fmaf(lm * Rc.z, Tp[100], acc);
            acc = fmaf(lm * Rc.w, Tp[110], acc);
            acc = fmaf(lm * Rd.x, Tp[120], acc);
            acc = fmaf(lm * Rd.y, Tp[130], acc);
            acc = fmaf(lm * Rd.z, Tp[140], acc);
            acc = fmaf(lm * Rd.w, Tp[150], acc);
        }
        OUT[(b0 + sm) * 10 + l] = acc;
    }
}

extern "C" void kernel_launch(void* const* d_in, const int* in_sizes, int n_in,
                              void* d_out, int out_size, void* d_ws, size_t ws_size,
                              hipStream_t stream)
{
    const float* X  = (const float*)d_in[0];   // (2048,196,2)
    const float* AL = (const float*)d_in[1];   // (2,16)
    const float* AM = (const float*)d_in[2];   // (194,2,16,16)
    const float* AR = (const float*)d_in[3];   // (2,16)
    const float* T  = (const float*)d_in[4];   // (16,16,10)
    (void)in_sizes; (void)n_in; (void)out_size; (void)ws_size;
    float* WS  = (float*)d_ws;                 // 2*100*512 floats = 400 KB
    float* OUT = (float*)d_out;                // (2048,10)

    hipLaunchKernelGGL(perm_kernel, dim3(388), dim3(256), 0, stream, AM, WS);
    hipLaunchKernelGGL(QuantumDMRGLayer_kernel, dim3(512), dim3(128), 0, stream,
                       X, AL, AR, T, WS, OUT);
}

// Round 6
// 103.096 us; speedup vs baseline: 1.0879x; 1.0032x over previous
//
#include <hip/hip_runtime.h>

// QuantumDMRGLayer: B=2048, L=196, M=16, NBL=10, pos_label=98 (fixed by setup).
// Round-6 = round-5 + bank-conflict fix. Round-5 measured 43.7 us with
// SQ_LDS_BANK_CONFLICT = 9.6M: lane n's fragment row at float offset n*16 put
// every ds_read_b128's 16 distinct reads on 8 banks (8-way conflict, 2.94x,
// model-matched the 43.7 us). Fix: per-lane ROTATED slot layout, baked into WS
// by the prep kernel (global_load_lds fill stays contiguous):
//   site block = 512 floats; lane n's row = 32 floats at n*32 (2 matrices x
//   4 quads); logical quad q stored at position (q+n)&7. pre() reads quad q at
//   offset ((q+n)&7)*4 -> bank 4*((q+n)&7): 8 quad-positions cover all 32
//   banks, 2 lanes each (2-way aliasing = free), same address across the 4
//   sample groups (broadcast).
// Everything else as round-5: __launch_bounds__(128,1) so the register
// pipeline exists; barrier-free double-buffered LDS chunks (wave fills & reads
// only its own stream region) via global_load_lds_dwordx4; explicit
// s_waitcnt vmcnt(0) issued 3 sites after each fill; DPP row_ror m-sum
// (dst[i]=src[(i-r)&15]); 4 independent FMA chains.

#define XR 392                 // floats per sample row of inputs (196*2)
#define SITE_F 512             // floats per site per stream (2 matrices x 256)
#define STRM_F (100 * SITE_F)  // padded stream region in WS
#define CHF 2048               // floats per 4-site chunk per stream

#define DPPV(r) __int_as_float(__builtin_amdgcn_update_dpp(                    \
    __float_as_int(v), __float_as_int(v), 0x120 + (r), 0xF, 0xF, false))
#define PIN(q) asm volatile("" : "+v"(q.x), "+v"(q.y), "+v"(q.z), "+v"(q.w))

typedef const __attribute__((address_space(1))) unsigned int* gptr_t;
typedef __attribute__((address_space(3))) unsigned int* lptr_t;

// ---- prep: permute A_mid (194,2,16,16) into rotated-slot layout in WS ----
// slot value for (stream, site p, lane n, slot r, matrix d):
//   left  = AM[p,     d, (n-r)&15, n]
//   right = AM[193-p, d, n, (n-r)&15]
// stored at  p*512 + n*32 + ((q+n)&7)*4 + e,  q = d*4 + (r>>2), e = r&3.
__global__ __launch_bounds__(256)
void perm_kernel(const float* __restrict__ AM, float* __restrict__ WS)
{
    const int bid = blockIdx.x;            // 0..387
    const int tid = threadIdx.x;           // 0..255 = n*16 + r
    const int n = tid >> 4, r = tid & 15;
    const int k = (bid < 196) ? bid : bid - 196;
    const int strm = (bid < 196) ? 0 : 1;
    const int p = k >> 1, d = k & 1;
    float val;
    if (strm == 0) {
        val = AM[p * 512 + d * 256 + ((n - r) & 15) * 16 + n];
    } else {
        val = AM[(193 - p) * 512 + d * 256 + n * 16 + ((n - r) & 15)];
    }
    const int q   = d * 4 + (r >> 2);
    const int pos = n * 32 + (((q + n) & 7) << 2) + (r & 3);
    WS[strm * STRM_F + p * SITE_F + pos] = val;
}

__global__ __launch_bounds__(128, 1)
void QuantumDMRGLayer_kernel(const float* __restrict__ X,
                             const float* __restrict__ AL,
                             const float* __restrict__ AR,
                             const float* __restrict__ T,
                             const float* __restrict__ WS,
                             float* __restrict__ OUT)
{
    __shared__ __align__(16) float sB[2][2][CHF];  // [buf][strm][...] 32 KB
    __shared__ __align__(16) float sX[4 * XR];     // 4 sample rows of inputs
    __shared__ __align__(16) float sT[2560];       // T_out (16,16,10)
    __shared__ float sV[4][2][16];                 // final vectors per sample

    const int tid  = threadIdx.x;
    const int wv   = tid >> 6;        // 0 = left sweep wave, 1 = right
    const int lane = tid & 63;
    const int g    = lane >> 4;       // sample slot 0..3 within block
    const int n    = lane & 15;       // vector component owned by this lane
    const int b0   = (int)blockIdx.x << 2;

    // ---- prologue: stage x rows and T_out ----
    for (int k = tid; k < 4 * 98; k += 128) {
        const int smp = k / 98, w = k - smp * 98;
        const float4 v4 = ((const float4*)(X + (size_t)(b0 + smp) * XR))[w];
        ((float4*)(sX + smp * XR))[w] = v4;
    }
    for (int k = tid; k < 640; k += 128)
        ((float4*)sT)[k] = ((const float4*)T)[k];
    __syncthreads();

    // ---- init bond vector ----
    const float* Ab = (wv == 0) ? AL : AR;
    const float2 x0 = *(const float2*)(sX + g * XR + (wv == 0 ? 0 : 390));
    float v = x0.x * Ab[n] + x0.y * Ab[16 + n];
    const float* xg = sX + g * XR;
    const float* Wb = WS + (wv ? STRM_F : 0);

    // per-lane rotated quad offsets (float units), loop-invariant
    int qoff[8];
#pragma unroll
    for (int q = 0; q < 8; ++q) qoff[q] = (((q + n) & 7) << 2);

    // fill chunk c (4 sites of this wave's stream) into LDS buffer buf.
    auto fill = [&](int c, int buf) {
        const float* gp = Wb + c * CHF + lane * 4;
        float* lp = &sB[buf][wv][0];
#pragma unroll
        for (int i = 0; i < 8; ++i)
            __builtin_amdgcn_global_load_lds((gptr_t)(gp + i * 256),
                                             (lptr_t)(lp + i * 256), 16, 0, 0);
    };
    // prefetch site j of buffer buf into 8 float4 (conflict-free b128 reads).
    auto pre = [&](float4* Q, int buf, int j) {
        const float* rp = &sB[buf][wv][j * SITE_F] + n * 32;
#pragma unroll
        for (int q = 0; q < 8; ++q)
            Q[q] = *(const float4*)(rp + qoff[q]);
    };
    // one site update: v <- x0*(sum_r v_rot(r)*mat0[n][r]) + x1*(...mat1...)
    auto step = [&](float4* Q, int p) {
        PIN(Q[0]); PIN(Q[1]); PIN(Q[2]); PIN(Q[3]);
        PIN(Q[4]); PIN(Q[5]); PIN(Q[6]); PIN(Q[7]);
        const int xo = (wv == 0) ? (2 + 2 * p) : (388 - 2 * p);
        const float2 xs = *(const float2*)(xg + xo);
        const float t1 = DPPV(1),  t2 = DPPV(2),  t3 = DPPV(3),  t4 = DPPV(4);
        const float t5 = DPPV(5),  t6 = DPPV(6),  t7 = DPPV(7),  t8 = DPPV(8);
        const float t9 = DPPV(9),  t10 = DPPV(10), t11 = DPPV(11), t12 = DPPV(12);
        const float t13 = DPPV(13), t14 = DPPV(14), t15 = DPPV(15);
        float a0 = v * Q[0].x;                 float c0 = v * Q[4].x;
        float a1 = t1 * Q[0].y;                float c1 = t1 * Q[4].y;
        a0 = fmaf(t2,  Q[0].z, a0);            c0 = fmaf(t2,  Q[4].z, c0);
        a1 = fmaf(t3,  Q[0].w, a1);            c1 = fmaf(t3,  Q[4].w, c1);
        a0 = fmaf(t4,  Q[1].x, a0);            c0 = fmaf(t4,  Q[5].x, c0);
        a1 = fmaf(t5,  Q[1].y, a1);            c1 = fmaf(t5,  Q[5].y, c1);
        a0 = fmaf(t6,  Q[1].z, a0);            c0 = fmaf(t6,  Q[5].z, c0);
        a1 = fmaf(t7,  Q[1].w, a1);            c1 = fmaf(t7,  Q[5].w, c1);
        a0 = fmaf(t8,  Q[2].x, a0);            c0 = fmaf(t8,  Q[6].x, c0);
        a1 = fmaf(t9,  Q[2].y, a1);            c1 = fmaf(t9,  Q[6].y, c1);
        a0 = fmaf(t10, Q[2].z, a0);            c0 = fmaf(t10, Q[6].z, c0);
        a1 = fmaf(t11, Q[2].w, a1);            c1 = fmaf(t11, Q[6].w, c1);
        a0 = fmaf(t12, Q[3].x, a0);            c0 = fmaf(t12, Q[7].x, c0);
        a1 = fmaf(t13, Q[3].y, a1);            c1 = fmaf(t13, Q[7].y, c1);
        a0 = fmaf(t14, Q[3].z, a0);            c0 = fmaf(t14, Q[7].z, c0);
        a1 = fmaf(t15, Q[3].w, a1);            c1 = fmaf(t15, Q[7].w, c1);
        v = fmaf(xs.x, a0 + a1, xs.y * (c0 + c1));
    };

    // ---- software-pipelined chain: 24 chunks x 4 sites, no barriers ----
    fill(0, 0);
    asm volatile("s_waitcnt vmcnt(0)" ::: "memory");
    float4 QA[8], QB[8];
    pre(QA, 0, 0);
    for (int c = 0; c < 24; ++c) {
        const int buf = c & 1;
        fill(c + 1, buf ^ 1);            // c=23: chunk 24 (right = pad, unused)
        pre(QB, buf, 1); step(QA, 4 * c);
        pre(QA, buf, 2); step(QB, 4 * c + 1);
        pre(QB, buf, 3); step(QA, 4 * c + 2);
        asm volatile("s_waitcnt vmcnt(0)" ::: "memory");
        pre(QA, buf ^ 1, 0); step(QB, 4 * c + 3);
    }
    // left stream has 2 extra sites (96, 97) in chunk 24 (buf 0)
    if (wv == 0) {
        pre(QB, 0, 1); step(QA, 96);
        step(QB, 97);
    }

    // ---- epilogue: out[b][l] = sum_{m,n} left[m] T[m][n][l] right[n] ----
    sV[g][wv][n] = v;
    __syncthreads();
    if (tid < 40) {
        const int sm = tid / 10;
        const int l  = tid - sm * 10;
        const float* Rv = &sV[sm][1][0];
        const float4 Ra = *(const float4*)(Rv);
        const float4 Rb = *(const float4*)(Rv + 4);
        const float4 Rc = *(const float4*)(Rv + 8);
        const float4 Rd = *(const float4*)(Rv + 12);
        float acc = 0.f;
#pragma unroll
        for (int m = 0; m < 16; ++m) {
            const float lm = sV[sm][0][m];
            const float* Tp = sT + m * 160 + l;
            acc = fmaf(lm * Ra.x, Tp[0],   acc);
            acc = fmaf(lm * Ra.y, Tp[10],  acc);
            acc = fmaf(lm * Ra.z, Tp[20],  acc);
            acc = fmaf(lm * Ra.w, Tp[30],  acc);
            acc = fmaf(lm * Rb.x, Tp[40],  acc);
            acc = fmaf(lm * Rb.y, Tp[50],  acc);
            acc = fmaf(lm * Rb.z, Tp[60],  acc);
            acc = fmaf(lm * Rb.w, Tp[70],  acc);
            acc = fmaf(lm * Rc.x, Tp[80],  acc);
            acc = fmaf(lm * Rc.y, Tp[90],  acc);
            acc = fmaf(lm * Rc.z, Tp[100], acc);
            acc = fmaf(lm * Rc.w, Tp[110], acc);
            acc = fmaf(lm * Rd.x, Tp[120], acc);
            acc = fmaf(lm * Rd.y, Tp[130], acc);
            acc = fmaf(lm * Rd.z, Tp[140], acc);
            acc = fmaf(lm * Rd.w, Tp[150], acc);
        }
        OUT[(b0 + sm) * 10 + l] = acc;
    }
}

extern "C" void kernel_launch(void* const* d_in, const int* in_sizes, int n_in,
                              void* d_out, int out_size, void* d_ws, size_t ws_size,
                              hipStream_t stream)
{
    const float* X  = (const float*)d_in[0];   // (2048,196,2)
    const float* AL = (const float*)d_in[1];   // (2,16)
    const float* AM = (const float*)d_in[2];   // (194,2,16,16)
    const float* AR = (const float*)d_in[3];   // (2,16)
    const float* T  = (const float*)d_in[4];   // (16,16,10)
    (void)in_sizes; (void)n_in; (void)out_size; (void)ws_size;
    float* WS  = (float*)d_ws;                 // 2*100*512 floats = 400 KB
    float* OUT = (float*)d_out;                // (2048,10)

    hipLaunchKernelGGL(perm_kernel, dim3(388), dim3(256), 0, stream, AM, WS);
    hipLaunchKernelGGL(QuantumDMRGLayer_kernel, dim3(512), dim3(128), 0, stream,
                       X, AL, AR, T, WS, OUT);
}

// Round 7
// 87.450 us; speedup vs baseline: 1.2825x; 1.1789x over previous
//
#include <hip/hip_runtime.h>

// QuantumDMRGLayer: B=2048, L=196, M=16, NBL=10, pos_label=98 (fixed by setup).
// Round-7: rounds 1-6 proved the 16-lane-per-chain mapping is latency-doomed:
// 1024 waves = exactly 1 wave/SIMD, zero TLP, ~1000 cyc/site regardless of
// inner-loop structure. This version batches 32 SAMPLES per wave and uses the
// fact that site weights are sample-shared: site update = D(32x32) =
// G(32x16) x V(16comps x 32samples) via v_mfma_f32_32x32x16_bf16, split-bf16
// (hi/lo) for accuracy: D = Ghi*Vhi + Ghi*Vlo + Glo*Vhi (3 MFMAs/site).
//   - G rows = [W0 | W1] outputs (d = row>>4), with a bit2<->bit3 row
//     permutation baked in at prep time so each lane's D regs = exactly its
//     own B-operand k-half: combine w[j] = x0*D[j] + x1*D[j+8] gives comps
//     k = 8*(lane>>5)+j  -> ZERO cross-lane ops in the chain.
//   - A-fragment stream (hi|lo per site, 2 KB) prepped in d_ws, read
//     global->VGPR with a 4-site ring (2x dwordx4 + 1x dwordx2 per site).
//   - 128 blocks x 64 threads (1 wave): block = (sample-group, direction).
//     Final states written to d_ws; small out_kernel does the T contraction.

typedef __attribute__((ext_vector_type(8))) short short8;
typedef __attribute__((ext_vector_type(16))) float floatx16;

#define GSITE_DW 512                 // dwords per site (hi 256 | lo 256)
#define GDIR_DW (100 * GSITE_DW)     // 100 sites per dir (2 pad)
#define STATE_DW (2 * GDIR_DW)       // float offset of state in d_ws
// state: [dir][2048][16] floats

__device__ __forceinline__ unsigned bf16_rne(unsigned u) {
    return (u + 0x7FFFu + ((u >> 16) & 1u)) >> 16;
}

// ---- prep: build split-bf16, row-permuted G streams in d_ws ----
// lane l holds A-operand row r=l&31, k = 8*(l>>5)+j.  Stored value =
// G[pi(r), k],  pi = swap bits 2<->3 of low nibble (keeps bit4 = d).
//   left  (site p):    G[(d,nn),k] = AM[p,      d, k, nn]
//   right (site 193-p):G[(d,nn),k] = AM[193-p,  d, nn, k]
__global__ __launch_bounds__(256)
void prep_kernel(const float* __restrict__ AM, unsigned* __restrict__ WS)
{
    int t = blockIdx.x * 256 + threadIdx.x;    // < 51200
    const int w    = t & 3;  t >>= 2;          // dword pair index 0..3
    const int lane = t & 63; t >>= 6;
    const int p    = t % 100;
    const int dir  = t / 100;
    const int kb = (lane >> 5) << 3;
    const int r  = lane & 31;
    const int rr = (r & 0x13) | ((r & 4) << 1) | ((r & 8) >> 1);  // pi(r)
    const int d = rr >> 4, nn = rr & 15;
    const int lim = dir ? 96 : 98;
    const int a = dir ? (193 - p) : p;
    const int k0 = kb + 2 * w;
    float g0 = 0.f, g1 = 0.f;
    if (p < lim) {
        const float* Ab = AM + a * 512 + d * 256;
        if (dir == 0) { g0 = Ab[k0 * 16 + nn]; g1 = Ab[(k0 + 1) * 16 + nn]; }
        else          { g0 = Ab[nn * 16 + k0]; g1 = Ab[nn * 16 + k0 + 1]; }
    }
    const unsigned u0 = __float_as_uint(g0), u1 = __float_as_uint(g1);
    const unsigned h0 = bf16_rne(u0), h1 = bf16_rne(u1);
    const float l0f = g0 - __uint_as_float(h0 << 16);
    const float l1f = g1 - __uint_as_float(h1 << 16);
    const unsigned lo0 = bf16_rne(__float_as_uint(l0f));
    const unsigned lo1 = bf16_rne(__float_as_uint(l1f));
    unsigned* gp = WS + (dir * 100 + p) * GSITE_DW;
    gp[lane * 4 + w]       = (h1 << 16) | h0;
    gp[256 + lane * 4 + w] = (lo1 << 16) | lo0;
}

// ---- main chain: 1 wave = 32 samples x 1 direction ----
__global__ __launch_bounds__(64, 1)
void chain_kernel(const float* __restrict__ X,
                  const float* __restrict__ AL,
                  const float* __restrict__ AR,
                  const unsigned* __restrict__ WS,
                  float* __restrict__ WST)
{
    const int lane = threadIdx.x;              // 0..63
    const int dir  = blockIdx.x & 1;
    const int s    = (blockIdx.x >> 1) * 32 + (lane & 31);
    const int kb   = (lane >> 5) << 3;         // this lane's k-half base
    const float* Xs = X + s * 392;
    const unsigned* Gb = WS + dir * GDIR_DW + lane * 4;
    const int lim = dir ? 96 : 98;

    // split fp32 comps -> packed bf16 hi/lo fragments (hi trunc, lo exact
    // by Sterbenz, lo trunc residual ~2^-17)
    float w[8];
    int4 vh4, vl4;
    auto pack = [&]() {
#pragma unroll
        for (int q = 0; q < 4; ++q) {
            const unsigned u0 = __float_as_uint(w[2 * q]);
            const unsigned u1 = __float_as_uint(w[2 * q + 1]);
            const unsigned h0 = u0 & 0xFFFF0000u, h1 = u1 & 0xFFFF0000u;
            const float l0 = w[2 * q]     - __uint_as_float(h0);
            const float l1 = w[2 * q + 1] - __uint_as_float(h1);
            ((unsigned*)&vh4)[q] = h1 | (h0 >> 16);
            ((unsigned*)&vl4)[q] = (__float_as_uint(l1) & 0xFFFF0000u) |
                                   (__float_as_uint(l0) >> 16);
        }
    };

    // ---- init bond vector: v[k] = x0*Ai[0][k] + x1*Ai[1][k] ----
    const float* Ai = dir ? AR : AL;
    const float2 xi = *(const float2*)(Xs + (dir ? 390 : 0));
#pragma unroll
    for (int j = 0; j < 8; ++j)
        w[j] = xi.x * Ai[kb + j] + xi.y * Ai[16 + kb + j];
    pack();

    // ---- 4-site register ring ----
    int4 GH[4], GL[4];
    float2 xr[4];
#pragma unroll
    for (int i = 0; i < 4; ++i) {
        GH[i] = *(const int4*)(Gb + i * GSITE_DW);
        GL[i] = *(const int4*)(Gb + i * GSITE_DW + 256);
        xr[i] = *(const float2*)(Xs + (dir ? (388 - 2 * i) : (2 + 2 * i)));
    }

    for (int c = 0; c < 25; ++c) {
#pragma unroll
        for (int j4 = 0; j4 < 4; ++j4) {
            const int p = 4 * c + j4;          // slot = p & 3 = j4
            if (p < lim) {
                const short8 ah = *(short8*)&GH[j4];
                const short8 al = *(short8*)&GL[j4];
                const short8 bh = *(short8*)&vh4;
                const short8 bl = *(short8*)&vl4;
                floatx16 D = {};
                D = __builtin_amdgcn_mfma_f32_32x32x16_bf16(ah, bh, D, 0, 0, 0);
                D = __builtin_amdgcn_mfma_f32_32x32x16_bf16(ah, bl, D, 0, 0, 0);
                D = __builtin_amdgcn_mfma_f32_32x32x16_bf16(al, bh, D, 0, 0, 0);
                const float2 xs = xr[j4];
#pragma unroll
                for (int j = 0; j < 8; ++j)        // D[j]=W0, D[j+8]=W1, k=kb+j
                    w[j] = fmaf(xs.x, D[j], xs.y * D[j + 8]);
                pack();
            }
            // prefetch site p+4 into this slot (pad sites 98,99 exist)
            const int pn = (p + 4 < 100) ? p + 4 : 99;
            GH[j4] = *(const int4*)(Gb + pn * GSITE_DW);
            GL[j4] = *(const int4*)(Gb + pn * GSITE_DW + 256);
            xr[j4] = *(const float2*)(Xs + (dir ? (388 - 2 * pn) : (2 + 2 * pn)));
        }
    }

    // ---- final state (fp32): comps kb..kb+7 of sample s ----
    float* st = WST + (dir * 2048 + s) * 16 + kb;
    *(float4*)(st)     = make_float4(w[0], w[1], w[2], w[3]);
    *(float4*)(st + 4) = make_float4(w[4], w[5], w[6], w[7]);
}

// ---- epilogue: out[s,l] = sum_{m,n} L[m,s] T[m,n,l] R[n,s] ----
__global__ __launch_bounds__(256)
void out_kernel(const float* __restrict__ T, const float* __restrict__ WST,
                float* __restrict__ OUT)
{
    __shared__ float sT[2560];
    const int tid = threadIdx.x;
    for (int k = tid; k < 640; k += 256)
        ((float4*)sT)[k] = ((const float4*)T)[k];
    __syncthreads();
    const int t = blockIdx.x * 256 + tid;      // < 20480
    const int s = t / 10, l = t - s * 10;
    const float* L = WST + s * 16;
    const float* R = WST + 2048 * 16 + s * 16;
    const float4 Ra = *(const float4*)(R);
    const float4 Rb = *(const float4*)(R + 4);
    const float4 Rc = *(const float4*)(R + 8);
    const float4 Rd = *(const float4*)(R + 12);
    float acc = 0.f;
#pragma unroll
    for (int m = 0; m < 16; ++m) {
        const float lm = L[m];
        const float* Tp = sT + m * 160 + l;
        acc = fmaf(lm * Ra.x, Tp[0],   acc);
        acc = fmaf(lm * Ra.y, Tp[10],  acc);
        acc = fmaf(lm * Ra.z, Tp[20],  acc);
        acc = fmaf(lm * Ra.w, Tp[30],  acc);
        acc = fmaf(lm * Rb.x, Tp[40],  acc);
        acc = fmaf(lm * Rb.y, Tp[50],  acc);
        acc = fmaf(lm * Rb.z, Tp[60],  acc);
        acc = fmaf(lm * Rb.w, Tp[70],  acc);
        acc = fmaf(lm * Rc.x, Tp[80],  acc);
        acc = fmaf(lm * Rc.y, Tp[90],  acc);
        acc = fmaf(lm * Rc.z, Tp[100], acc);
        acc = fmaf(lm * Rc.w, Tp[110], acc);
        acc = fmaf(lm * Rd.x, Tp[120], acc);
        acc = fmaf(lm * Rd.y, Tp[130], acc);
        acc = fmaf(lm * Rd.z, Tp[140], acc);
        acc = fmaf(lm * Rd.w, Tp[150], acc);
    }
    OUT[t] = acc;
}

extern "C" void kernel_launch(void* const* d_in, const int* in_sizes, int n_in,
                              void* d_out, int out_size, void* d_ws, size_t ws_size,
                              hipStream_t stream)
{
    const float* X  = (const float*)d_in[0];   // (2048,196,2)
    const float* AL = (const float*)d_in[1];   // (2,16)
    const float* AM = (const float*)d_in[2];   // (194,2,16,16)
    const float* AR = (const float*)d_in[3];   // (2,16)
    const float* T  = (const float*)d_in[4];   // (16,16,10)
    (void)in_sizes; (void)n_in; (void)out_size; (void)ws_size;
    unsigned* WS = (unsigned*)d_ws;            // G streams: 400 KB
    float* WST   = (float*)d_ws + STATE_DW;    // states: 256 KB
    float* OUT   = (float*)d_out;              // (2048,10)

    hipLaunchKernelGGL(prep_kernel,  dim3(200), dim3(256), 0, stream, AM, WS);
    hipLaunchKernelGGL(chain_kernel, dim3(128), dim3(64),  0, stream,
                       X, AL, AR, WS, WST);
    hipLaunchKernelGGL(out_kernel,   dim3(80),  dim3(256), 0, stream,
                       T, WST, OUT);
}